// Round 4
// baseline (580.802 us; speedup 1.0000x reference)
//
#include <hip/hip_runtime.h>
#include <cstdint>
#include <cstddef>

#define BN_EPS 1e-5f
#define BKT 256        // buckets (dst>>9), 512 nodes each; 100000>>9 = 195 -> 196 used
#define BSH 9
#define CHUNK 8192     // edges per block in hist/scatter

typedef __attribute__((ext_vector_type(8))) short bf16x8;   // 8 bf16 = 4 VGPRs
typedef __attribute__((ext_vector_type(4))) float f32x4;    // MFMA acc

// ---- manual bf16 helpers (hip_bf16.h intrinsics unavailable in this ROCm) ----
__device__ __forceinline__ unsigned int f32_to_bf16_rne(float f) {
    unsigned int u = __float_as_uint(f);
    u += 0x7FFFu + ((u >> 16) & 1u);
    return u >> 16;
}
__device__ __forceinline__ unsigned int pack_bf16x2(float a, float b) {
    return f32_to_bf16_rne(a) | (f32_to_bf16_rne(b) << 16);
}
__device__ __forceinline__ float bf16_lo(unsigned int p) { return __uint_as_float(p << 16); }
__device__ __forceinline__ float bf16_hi(unsigned int p) { return __uint_as_float(p & 0xFFFF0000u); }

// ---------------- bucketed CSR build ----------------
// Phase 1: per-(bucket,block) histogram H[b*G+g]
__global__ void hist_kernel(const int* __restrict__ dst, int* __restrict__ H, int e, int G) {
    __shared__ int h[BKT];
    int t = threadIdx.x, g = blockIdx.x;
    h[t] = 0;
    __syncthreads();
    int base = g * CHUNK;
#pragma unroll
    for (int i = 0; i < CHUNK / 256; i++) {
        int idx = base + i * 256 + t;
        if (idx < e) atomicAdd(&h[dst[idx] >> BSH], 1);
    }
    __syncthreads();
    H[t * G + g] = h[t];
}

// Phase 3: scatter (src,dst) into bucket-contiguous binned array.
__global__ void bin_scatter_kernel(const int* __restrict__ src, const int* __restrict__ dst,
                                   const int* __restrict__ Hscan, uint2* __restrict__ binned,
                                   int e, int G) {
    __shared__ int cur[BKT];
    int t = threadIdx.x, g = blockIdx.x;
    cur[t] = Hscan[t * G + g];
    __syncthreads();
    int base = g * CHUNK;
#pragma unroll
    for (int i = 0; i < CHUNK / 256; i++) {
        int idx = base + i * 256 + t;
        if (idx < e) {
            int s = src[idx], d = dst[idx];
            int pos = atomicAdd(&cur[d >> BSH], 1);
            uint2 v; v.x = (unsigned)s; v.y = (unsigned)d;
            binned[pos] = v;
        }
    }
}

// Phase 4: one block per bucket (512 nodes). Count degrees, local scan,
// write cnt/rowptr/dinv, then fill esrc -- all cursors/counts in LDS.
__global__ __launch_bounds__(256) void bucket_build_kernel(const uint2* __restrict__ binned,
                                                           const int* __restrict__ Hscan,
                                                           int* __restrict__ cnt,
                                                           int* __restrict__ rowptr,
                                                           float* __restrict__ dinv,
                                                           int* __restrict__ esrc,
                                                           int e, int G, int n) {
    __shared__ int lcnt[512], lexc[512], ssum[256];
    const int t = threadIdx.x;
    const int b = blockIdx.x;
    const int start = Hscan[b * G];
    const int end = (b == BKT - 1) ? e : Hscan[(b + 1) * G];

    lcnt[t] = 0; lcnt[t + 256] = 0;
    __syncthreads();
    for (int i = start + t; i < end; i += 256)
        atomicAdd(&lcnt[binned[i].y & 511], 1);
    __syncthreads();

    int a0 = lcnt[2 * t], a1 = lcnt[2 * t + 1];
    ssum[t] = a0 + a1;
    __syncthreads();
    for (int off = 1; off < 256; off <<= 1) {
        int v = (t >= off) ? ssum[t - off] : 0;
        __syncthreads();
        ssum[t] += v;
        __syncthreads();
    }
    int excl = (t == 0) ? 0 : ssum[t - 1];
    lexc[2 * t] = excl;
    lexc[2 * t + 1] = excl + a0;
    __syncthreads();

    int nodebase = b << BSH;
#pragma unroll
    for (int j2 = 0; j2 < 2; j2++) {
        int j = 2 * t + j2;
        int node = nodebase + j;
        if (node < n) {
            int c = lcnt[j];
            cnt[node] = c;
            rowptr[node] = start + lexc[j];
            dinv[node] = rsqrtf((float)(c + 1));
        }
    }
    __syncthreads();

    for (int i = start + t; i < end; i += 256) {
        uint2 ed = binned[i];
        int pos = start + atomicAdd(&lexc[ed.y & 511], 1);
        esrc[pos] = (int)ed.x;
    }
}

// ---- scan helpers for H (bucket-major (bucket,block) histogram) ----

__global__ void blocksum_kernel(const int* __restrict__ in, int* __restrict__ bsum, int n) {
    int t = threadIdx.x;
    int base = blockIdx.x * 1024 + t * 4;
    int s = 0;
    if (base + 3 < n) {
        int4 v = *(const int4*)&in[base];
        s = v.x + v.y + v.z + v.w;
    } else {
        for (int j = 0; j < 4; j++) if (base + j < n) s += in[base + j];
    }
    __shared__ int ls[256];
    ls[t] = s;
    __syncthreads();
    for (int off = 128; off > 0; off >>= 1) {
        if (t < off) ls[t] += ls[t + off];
        __syncthreads();
    }
    if (t == 0) bsum[blockIdx.x] = ls[0];
}

__global__ void scan_bsum_kernel(int* __restrict__ bsum, int nb) {
    int t = threadIdx.x;
    __shared__ int ls[256];
    int v = (t < nb) ? bsum[t] : 0;
    ls[t] = v;
    __syncthreads();
    for (int off = 1; off < 256; off <<= 1) {
        int p = (t >= off) ? ls[t - off] : 0;
        __syncthreads();
        ls[t] += p;
        __syncthreads();
    }
    if (t < nb) bsum[t] = ls[t] - v;   // inclusive -> exclusive
}

__global__ void scan_write1_kernel(const int* __restrict__ in, const int* __restrict__ bsum,
                                   int* __restrict__ out, int n) {
    int t = threadIdx.x;
    int base = blockIdx.x * 1024 + t * 4;
    int v[4];
    int s = 0;
    if (base + 3 < n) {
        int4 q = *(const int4*)&in[base];
        v[0] = q.x; v[1] = q.y; v[2] = q.z; v[3] = q.w;
        s = q.x + q.y + q.z + q.w;
    } else {
        for (int j = 0; j < 4; j++) { v[j] = (base + j < n) ? in[base + j] : 0; s += v[j]; }
    }
    __shared__ int ls[256];
    ls[t] = s;
    __syncthreads();
    for (int off = 1; off < 256; off <<= 1) {
        int p = (t >= off) ? ls[t - off] : 0;
        __syncthreads();
        ls[t] += p;
        __syncthreads();
    }
    int run = bsum[blockIdx.x] + ls[t] - s;
    if (base + 3 < n) {
        int4 r; r.x = run; r.y = run + v[0]; r.z = run + v[0] + v[1]; r.w = run + v[0] + v[1] + v[2];
        *(int4*)&out[base] = r;
    } else {
        for (int j = 0; j < 4; j++) {
            if (base + j < n) out[base + j] = run;
            run += v[j];
        }
    }
}

// ---------------- W fragment prep: W[128][OUTC] fp32 -> hi/lo bf16 MFMA B-fragments ----
// Layout: slot = (ct*4 + kc)*64 + lane; each slot holds 8 bf16 (16B):
//   element j: W[kc*32 + (lane>>4)*8 + j][ct*16 + (lane&15)]
// hi = bf16_rne(w), lo = bf16_rne(w - hi)  (split-precision operands).
// All three weight matrices prepped in ONE launch (20 blocks).

__device__ __forceinline__ void wprep_one(const float* __restrict__ W,
                                          uint4* __restrict__ whi, uint4* __restrict__ wlo,
                                          int slot, int OUTC) {
    int l  = slot & 63;
    int kc = (slot >> 6) & 3;
    int ct = slot >> 8;
    int c  = ct * 16 + (l & 15);
    int k0 = kc * 32 + (l >> 4) * 8;
    unsigned hi[4], lo[4];
#pragma unroll
    for (int jj = 0; jj < 4; jj++) {
        float v0 = W[(size_t)(k0 + 2 * jj) * OUTC + c];
        float v1 = W[(size_t)(k0 + 2 * jj + 1) * OUTC + c];
        unsigned h0 = f32_to_bf16_rne(v0), h1 = f32_to_bf16_rne(v1);
        float l0 = v0 - __uint_as_float(h0 << 16);
        float l1 = v1 - __uint_as_float(h1 << 16);
        hi[jj] = h0 | (h1 << 16);
        lo[jj] = pack_bf16x2(l0, l1);
    }
    uint4 uh; uh.x = hi[0]; uh.y = hi[1]; uh.z = hi[2]; uh.w = hi[3];
    uint4 ul; ul.x = lo[0]; ul.y = lo[1]; ul.z = lo[2]; ul.w = lo[3];
    whi[slot] = uh;
    wlo[slot] = ul;
}

__global__ void wprep_all_kernel(const float* __restrict__ W1, uint4* w1hi, uint4* w1lo,
                                 const float* __restrict__ W2, uint4* w2hi, uint4* w2lo,
                                 const float* __restrict__ W3, uint4* w3hi, uint4* w3lo) {
    int id = blockIdx.x * 256 + threadIdx.x;
    if (id < 2048)       wprep_one(W1, w1hi, w1lo, id, 128);
    else if (id < 4096)  wprep_one(W2, w2hi, w2lo, id - 2048, 128);
    else if (id < 5120)  wprep_one(W3, w3hi, w3lo, id - 4096, 64);
}

// ---------------- GEMM via bf16 MFMA (fp32-equivalent via hi/lo split) ----------------
// Y[n,OUTC](bf16, pre-scaled by dinv[row]) = dinv[r] * act(X[n,128]) @ W[128,OUTC]
// act = BN(scale,shift)+ReLU when scale!=nullptr, else identity.
// Per block: 64 rows x OUTC cols. 4 waves; wave w owns col-tiles {w*CTW .. }.
// Operands SWAPPED in mfma (W-frag as A, X-frag as B) so D is row-major per
// lane: lane holds 4 consecutive output cols of one row -> uint2 store.

template <int OUTC>
__global__ __launch_bounds__(256) void gemm_kernel(const float* __restrict__ X,
                                                   const uint4* __restrict__ whi,
                                                   const uint4* __restrict__ wlo,
                                                   const float* __restrict__ scale,
                                                   const float* __restrict__ shift,
                                                   const float* __restrict__ dinv,
                                                   unsigned int* __restrict__ Y, int n) {
    constexpr int NCT = OUTC / 16;
    constexpr int CTW = NCT / 4;   // col-tiles per wave (2 for OUTC=128, 1 for 64)
    __shared__ __align__(16) unsigned short lAhi[64 * 128];  // 16 KB, XOR-swizzled
    __shared__ __align__(16) unsigned short lAlo[64 * 128];  // 16 KB
    __shared__ float ldv[64];
    const int t = threadIdx.x;
    const int base = blockIdx.x * 64;
    const int lane = t & 63;
    const int w = t >> 6;
    const bool bn = (scale != nullptr);

    if (t < 64) { int r = base + t; ldv[t] = (r < n) ? dinv[r] : 0.0f; }

    // B fragments (registers, whole kernel): CTW x 4 kc x {hi,lo}
    bf16x8 bhi[CTW][4], blo[CTW][4];
#pragma unroll
    for (int c = 0; c < CTW; c++) {
        int ct = w * CTW + c;
#pragma unroll
        for (int kc = 0; kc < 4; kc++) {
            int slot = (ct * 4 + kc) * 64 + lane;
            bhi[c][kc] = *reinterpret_cast<const bf16x8*>(whi + slot);
            blo[c][kc] = *reinterpret_cast<const bf16x8*>(wlo + slot);
        }
    }

    // Stage A: coalesced fp32 loads, fused BN+ReLU, hi/lo bf16 split, swizzled LDS.
    const int col4 = (t & 31) * 4;
    float4 sc4, sh4;
    if (bn) {
        sc4 = *(const float4*)&scale[col4];
        sh4 = *(const float4*)&shift[col4];
    }
#pragma unroll
    for (int i = 0; i < 8; i++) {
        int row = i * 8 + (t >> 5);
        int r = base + row;
        float4 xv = make_float4(0.f, 0.f, 0.f, 0.f);
        if (r < n) xv = *(const float4*)&X[(size_t)r * 128 + col4];
        if (bn) {
            xv.x = fmaxf(fmaf(xv.x, sc4.x, sh4.x), 0.0f);
            xv.y = fmaxf(fmaf(xv.y, sc4.y, sh4.y), 0.0f);
            xv.z = fmaxf(fmaf(xv.z, sc4.z, sh4.z), 0.0f);
            xv.w = fmaxf(fmaf(xv.w, sc4.w, sh4.w), 0.0f);
        }
        unsigned h0 = f32_to_bf16_rne(xv.x), h1 = f32_to_bf16_rne(xv.y);
        unsigned h2 = f32_to_bf16_rne(xv.z), h3 = f32_to_bf16_rne(xv.w);
        float l0 = xv.x - __uint_as_float(h0 << 16);
        float l1 = xv.y - __uint_as_float(h1 << 16);
        float l2 = xv.z - __uint_as_float(h2 << 16);
        float l3 = xv.w - __uint_as_float(h3 << 16);
        uint2 ph; ph.x = h0 | (h1 << 16); ph.y = h2 | (h3 << 16);
        uint2 pl; pl.x = pack_bf16x2(l0, l1); pl.y = pack_bf16x2(l2, l3);
        int off = row * 256 + ((col4 * 2) ^ ((row & 7) << 4));
        *(uint2*)((char*)lAhi + off) = ph;
        *(uint2*)((char*)lAlo + off) = pl;
    }
    __syncthreads();

    // Compute: 4 row-tiles of 16; per (rt,kc): 2 LDS frag reads + 3*CTW MFMAs.
    const int arow = lane & 15;
    const int kb16 = (lane >> 4) * 16;
#pragma unroll
    for (int rt = 0; rt < 4; rt++) {
        f32x4 acc[CTW];
#pragma unroll
        for (int c = 0; c < CTW; c++) acc[c] = (f32x4){0.f, 0.f, 0.f, 0.f};
        int row = rt * 16 + arow;
        int rb = row * 256;
        int sw = (row & 7) << 4;
#pragma unroll
        for (int kc = 0; kc < 4; kc++) {
            int off = rb + ((kc * 64 + kb16) ^ sw);
            bf16x8 ah = *(const bf16x8*)((const char*)lAhi + off);
            bf16x8 al = *(const bf16x8*)((const char*)lAlo + off);
#pragma unroll
            for (int c = 0; c < CTW; c++) {
                acc[c] = __builtin_amdgcn_mfma_f32_16x16x32_bf16(bhi[c][kc], ah, acc[c], 0, 0, 0);
                acc[c] = __builtin_amdgcn_mfma_f32_16x16x32_bf16(blo[c][kc], ah, acc[c], 0, 0, 0);
                acc[c] = __builtin_amdgcn_mfma_f32_16x16x32_bf16(bhi[c][kc], al, acc[c], 0, 0, 0);
            }
        }
        int r = base + row;
        if (r < n) {
            float dv = ldv[row];
#pragma unroll
            for (int c = 0; c < CTW; c++) {
                int ct = w * CTW + c;
                uint2 o;
                o.x = pack_bf16x2(acc[c][0] * dv, acc[c][1] * dv);
                o.y = pack_bf16x2(acc[c][2] * dv, acc[c][3] * dv);
                *(uint2*)&Y[(size_t)r * (OUTC / 2) + ct * 8 + (lane >> 4) * 2] = o;
            }
        }
    }
}

// ---------------- aggregation (128 cols): TWO nodes per wave + fused BN stats ----------------
// xw rows are pre-scaled by dinv[src]. out[d] = dinv[d]*(sum xw'[s] + xw'[d]) + b.
// 32 lanes per node, uint2 (8B) gathers -> one wave-instruction fetches TWO
// 256B rows; 8-deep batch pipeline, clamped indices kill the tail.
// Epilogue: per-block LDS column sums (sum, sumsq) of the written h rows ->
// 8-sharded global atomic partials (bnpart[8][256]) for the BN-stats pass,
// eliminating the separate 51-MB bn_stats re-read.

__global__ __launch_bounds__(256) void agg128_kernel(const unsigned int* __restrict__ xw,
                                                     const int* __restrict__ rowptr,
                                                     const int* __restrict__ cnt,
                                                     const int* __restrict__ esrc,
                                                     const float* __restrict__ dinv,
                                                     const float* __restrict__ bias,
                                                     float* __restrict__ out,
                                                     float* __restrict__ bnpart, int n) {
    __shared__ float lsum[256];
    lsum[threadIdx.x] = 0.0f;

    const uint2* xw2 = (const uint2*)xw;
    int wid = (blockIdx.x * 256 + threadIdx.x) >> 6;   // wave index
    int lane = threadIdx.x & 63;
    int half = lane >> 5;
    int hl = lane & 31;
    int node = wid * 2 + half;
    bool ok = node < n;
    int nc = ok ? node : 0;

    float di = dinv[nc];
    int beg = rowptr[nc];
    int cv  = ok ? cnt[nc] : 0;
    int last = beg + cv - 1;
    int nb = (cv + 7) >> 3;

    uint2 ap = xw2[(size_t)nc * 32 + hl];
    float ax = bf16_lo(ap.x), ay = bf16_hi(ap.x);
    float az = bf16_lo(ap.y), aw = bf16_hi(ap.y);

    int s[8], sn[8];
    if (nb > 0) {
#pragma unroll
        for (int j = 0; j < 8; j++) {
            int idx = beg + j;
            s[j] = esrc[idx <= last ? idx : last];
        }
    }
    for (int b = 0; b < nb; b++) {
        int ebase = beg + b * 8;
        if (b + 1 < nb) {
#pragma unroll
            for (int j = 0; j < 8; j++) {
                int idx = ebase + 8 + j;
                sn[j] = esrc[idx <= last ? idx : last];
            }
        }
        uint2 v[8];
#pragma unroll
        for (int j = 0; j < 8; j++) v[j] = xw2[(size_t)s[j] * 32 + hl];
        int rem = last - ebase;   // valid j <= rem
#pragma unroll
        for (int j = 0; j < 8; j++) {
            float m = (j <= rem) ? 1.0f : 0.0f;
            ax = fmaf(m, bf16_lo(v[j].x), ax);
            ay = fmaf(m, bf16_hi(v[j].x), ay);
            az = fmaf(m, bf16_lo(v[j].y), az);
            aw = fmaf(m, bf16_hi(v[j].y), aw);
        }
        if (b + 1 < nb) {
#pragma unroll
            for (int j = 0; j < 8; j++) s[j] = sn[j];
        }
    }

    float4 o = make_float4(0.f, 0.f, 0.f, 0.f);
    if (ok) {
        float4 bv = ((const float4*)bias)[hl];
        o.x = fmaf(di, ax, bv.x);
        o.y = fmaf(di, ay, bv.y);
        o.z = fmaf(di, az, bv.z);
        o.w = fmaf(di, aw, bv.w);
        ((float4*)(out + (size_t)node * 128))[hl] = o;
    }

    // fused BN-stats partials (h includes bias, matching reference _bn input)
    __syncthreads();   // lsum init visible to all before atomics
    if (ok) {
        int c = hl * 4;
        atomicAdd(&lsum[c + 0], o.x);
        atomicAdd(&lsum[c + 1], o.y);
        atomicAdd(&lsum[c + 2], o.z);
        atomicAdd(&lsum[c + 3], o.w);
        atomicAdd(&lsum[128 + c + 0], o.x * o.x);
        atomicAdd(&lsum[128 + c + 1], o.y * o.y);
        atomicAdd(&lsum[128 + c + 2], o.z * o.z);
        atomicAdd(&lsum[128 + c + 3], o.w * o.w);
    }
    __syncthreads();
    atomicAdd(&bnpart[(blockIdx.x & 7) * 256 + threadIdx.x], lsum[threadIdx.x]);
}

// ---------------- aggregation (64-col output layer): TWO nodes per wave ----------------

__global__ __launch_bounds__(256) void agg64_kernel(const unsigned int* __restrict__ xw,
                                                    const int* __restrict__ rowptr,
                                                    const int* __restrict__ cnt,
                                                    const int* __restrict__ esrc,
                                                    const float* __restrict__ dinv,
                                                    const float* __restrict__ bias,
                                                    float* __restrict__ out, int n) {
    int wid = (blockIdx.x * 256 + threadIdx.x) >> 6;
    int lane = threadIdx.x & 63;
    int half = lane >> 5;
    int hl = lane & 31;
    int node = wid * 2 + half;
    bool ok = node < n;
    int nc = ok ? node : 0;

    float di = dinv[nc];
    int beg = rowptr[nc];
    int cv  = ok ? cnt[nc] : 0;
    int last = beg + cv - 1;
    int nb = (cv + 7) >> 3;

    unsigned int ap = xw[(size_t)nc * 32 + hl];
    float ax = bf16_lo(ap), ay = bf16_hi(ap);

    int s[8], sn[8];
    if (nb > 0) {
#pragma unroll
        for (int j = 0; j < 8; j++) {
            int idx = beg + j;
            s[j] = esrc[idx <= last ? idx : last];
        }
    }
    for (int b = 0; b < nb; b++) {
        int ebase = beg + b * 8;
        if (b + 1 < nb) {
#pragma unroll
            for (int j = 0; j < 8; j++) {
                int idx = ebase + 8 + j;
                sn[j] = esrc[idx <= last ? idx : last];
            }
        }
        unsigned int v[8];
#pragma unroll
        for (int j = 0; j < 8; j++) v[j] = xw[(size_t)s[j] * 32 + hl];
        int rem = last - ebase;
#pragma unroll
        for (int j = 0; j < 8; j++) {
            float m = (j <= rem) ? 1.0f : 0.0f;
            ax = fmaf(m, bf16_lo(v[j]), ax);
            ay = fmaf(m, bf16_hi(v[j]), ay);
        }
        if (b + 1 < nb) {
#pragma unroll
            for (int j = 0; j < 8; j++) s[j] = sn[j];
        }
    }
    if (ok) {
        float2 bv = ((const float2*)bias)[hl];
        float2 o;
        o.x = fmaf(di, ax, bv.x);
        o.y = fmaf(di, ay, bv.y);
        ((float2*)(out + (size_t)node * 64))[hl] = o;
    }
}

// ---------------- BN reduce + finalize (one tiny block; reads 8x256 partials) ----------------

__global__ void bnred_kernel(const float* __restrict__ part, const float* __restrict__ g,
                             const float* __restrict__ be, float* __restrict__ scale,
                             float* __restrict__ shift, int n) {
    int t = threadIdx.x;  // 256 threads
    float s = 0.0f;
#pragma unroll
    for (int k = 0; k < 8; k++) s += part[k * 256 + t];
    __shared__ float L[256];
    L[t] = s;
    __syncthreads();
    if (t < 128) {
        float inv_n = 1.0f / (float)n;
        float mean = L[t] * inv_n;
        float var = L[128 + t] * inv_n - mean * mean;
        float rstd = rsqrtf(var + BN_EPS);
        float sc = rstd * g[t];
        scale[t] = sc;
        shift[t] = be[t] - mean * sc;
    }
}

// ---------------- launch ----------------

extern "C" void kernel_launch(void* const* d_in, const int* in_sizes, int n_in,
                              void* d_out, int out_size, void* d_ws, size_t ws_size,
                              hipStream_t stream) {
    const float* x   = (const float*)d_in[0];
    const int*   ei  = (const int*)d_in[1];
    const float* W1  = (const float*)d_in[2];
    const float* b1  = (const float*)d_in[3];
    const float* g1  = (const float*)d_in[4];
    const float* be1 = (const float*)d_in[5];
    const float* W2  = (const float*)d_in[6];
    const float* b2  = (const float*)d_in[7];
    const float* g2  = (const float*)d_in[8];
    const float* be2 = (const float*)d_in[9];
    const float* W3  = (const float*)d_in[10];
    const float* b3  = (const float*)d_in[11];

    const int n = in_sizes[0] / 128;
    const int E = in_sizes[1] / 2;
    const int* srcv = ei;
    const int* dstv = ei + E;

    const int G = (E + CHUNK - 1) / CHUNK;      // hist/scatter blocks (196)
    const int HN = BKT * G;                      // H matrix elements (50176)
    const int NB = (n + 511) >> 9;               // used buckets (196)

    char* p = (char*)d_ws;
    auto carve = [&](size_t bytes) -> char* {
        char* q = p;
        p += (bytes + 255) & ~(size_t)255;
        return q;
    };
    int*   cnt    = (int*)carve((size_t)n * 4);
    int*   rowptr = (int*)carve((size_t)n * 4);
    float* dinv   = (float*)carve((size_t)n * 4);
    int*   esrc   = (int*)carve((size_t)E * 4);
    uint2* binned = (uint2*)carve((size_t)E * 8);
    int*   H      = (int*)carve((size_t)HN * 4);
    int*   Hscan  = (int*)carve((size_t)HN * 4);
    float* bnpart = (float*)carve(2 * 8 * 256 * 4);  // [layer][shard8][256] BN partials
    float* bnsc   = (float*)carve(512 * 4);          // [scale1|shift1|scale2|shift2]
    int*   bsum   = (int*)carve(1024 * 4);
    uint4* w1hi   = (uint4*)carve(2048 * 16); // W-frag arrays (hi/lo bf16)
    uint4* w1lo   = (uint4*)carve(2048 * 16);
    uint4* w2hi   = (uint4*)carve(2048 * 16);
    uint4* w2lo   = (uint4*)carve(2048 * 16);
    uint4* w3hi   = (uint4*)carve(1024 * 16);
    uint4* w3lo   = (uint4*)carve(1024 * 16);
    unsigned int* xwb = (unsigned int*)carve((size_t)n * 128 * 2);  // gemm out (bf16 packed, pre-scaled by dinv)
    float* bufB   = (float*)carve((size_t)n * 128 * 4);             // agg out (fp32)

    hipMemsetAsync(bnpart, 0, 2 * 8 * 256 * 4, stream);

    int sbH = (HN + 1023) / 1024;    // 49 <= 256

    // W fragment prep, single launch (no deps; overlaps CSR build region)
    wprep_all_kernel<<<20, 256, 0, stream>>>(W1, w1hi, w1lo, W2, w2hi, w2lo, W3, w3hi, w3lo);

    // bucketed CSR build (single LDS-atomic build kernel; no global N-scan)
    hist_kernel<<<G, 256, 0, stream>>>(dstv, H, E, G);
    blocksum_kernel<<<sbH, 256, 0, stream>>>(H, bsum, HN);
    scan_bsum_kernel<<<1, 256, 0, stream>>>(bsum, sbH);
    scan_write1_kernel<<<sbH, 256, 0, stream>>>(H, bsum, Hscan, HN);
    bin_scatter_kernel<<<G, 256, 0, stream>>>(srcv, dstv, Hscan, binned, E, G);
    bucket_build_kernel<<<NB, 256, 0, stream>>>(binned, Hscan, cnt, rowptr, dinv, esrc, E, G, n);

    int gb = (n + 63) / 64;
    int ab = (n + 7) / 8;   // 2 nodes per wave, 4 waves per block

    // layer 1: gcn(x, W1) + b1  (agg epilogue accumulates BN partials)
    gemm_kernel<128><<<gb, 256, 0, stream>>>(x, w1hi, w1lo, nullptr, nullptr, dinv, xwb, n);
    agg128_kernel<<<ab, 256, 0, stream>>>(xwb, rowptr, cnt, esrc, dinv, b1, bufB, bnpart, n);
    bnred_kernel<<<1, 256, 0, stream>>>(bnpart, g1, be1, bnsc, bnsc + 128, n);

    // layer 2: gcn(relu(bn1(h)), W2) + b2   (bn1+relu fused into gemm staging)
    gemm_kernel<128><<<gb, 256, 0, stream>>>(bufB, w2hi, w2lo, bnsc, bnsc + 128, dinv, xwb, n);
    agg128_kernel<<<ab, 256, 0, stream>>>(xwb, rowptr, cnt, esrc, dinv, b2, bufB, bnpart + 2048, n);
    bnred_kernel<<<1, 256, 0, stream>>>(bnpart + 2048, g2, be2, bnsc + 256, bnsc + 384, n);

    // layer 3: gcn(relu(bn2(h)), W3) + b3  -> d_out
    gemm_kernel<64><<<gb, 256, 0, stream>>>(bufB, w3hi, w3lo, bnsc + 256, bnsc + 384, dinv, xwb, n);
    agg64_kernel<<<ab, 256, 0, stream>>>(xwb, rowptr, cnt, esrc, dinv, b3, (float*)d_out, n);
}

// Round 6
// 504.744 us; speedup vs baseline: 1.1507x; 1.1507x over previous
//
#include <hip/hip_runtime.h>
#include <cstdint>
#include <cstddef>

#define BN_EPS 1e-5f
#define BKT 256        // buckets (dst>>9), 512 nodes each; 100000>>9 = 195 -> 196 used
#define BSH 9
#define CHUNK 8192     // edges per block in hist/scatter

typedef __attribute__((ext_vector_type(8))) short bf16x8;   // 8 bf16 = 4 VGPRs
typedef __attribute__((ext_vector_type(4))) float f32x4;    // MFMA acc

// ---- manual bf16 helpers (hip_bf16.h intrinsics unavailable in this ROCm) ----
__device__ __forceinline__ unsigned int f32_to_bf16_rne(float f) {
    unsigned int u = __float_as_uint(f);
    u += 0x7FFFu + ((u >> 16) & 1u);
    return u >> 16;
}
__device__ __forceinline__ unsigned int pack_bf16x2(float a, float b) {
    return f32_to_bf16_rne(a) | (f32_to_bf16_rne(b) << 16);
}
__device__ __forceinline__ float bf16_lo(unsigned int p) { return __uint_as_float(p << 16); }
__device__ __forceinline__ float bf16_hi(unsigned int p) { return __uint_as_float(p & 0xFFFF0000u); }

// ---------------- bucketed CSR build ----------------
// Phase 1: per-(bucket,block) histogram H[b*G+g]
__global__ void hist_kernel(const int* __restrict__ dst, int* __restrict__ H, int e, int G) {
    __shared__ int h[BKT];
    int t = threadIdx.x, g = blockIdx.x;
    h[t] = 0;
    __syncthreads();
    int base = g * CHUNK;
#pragma unroll
    for (int i = 0; i < CHUNK / 256; i++) {
        int idx = base + i * 256 + t;
        if (idx < e) atomicAdd(&h[dst[idx] >> BSH], 1);
    }
    __syncthreads();
    H[t * G + g] = h[t];
}

// Phase 3: scatter (src,dst) into bucket-contiguous binned array.
__global__ void bin_scatter_kernel(const int* __restrict__ src, const int* __restrict__ dst,
                                   const int* __restrict__ Hscan, uint2* __restrict__ binned,
                                   int e, int G) {
    __shared__ int cur[BKT];
    int t = threadIdx.x, g = blockIdx.x;
    cur[t] = Hscan[t * G + g];
    __syncthreads();
    int base = g * CHUNK;
#pragma unroll
    for (int i = 0; i < CHUNK / 256; i++) {
        int idx = base + i * 256 + t;
        if (idx < e) {
            int s = src[idx], d = dst[idx];
            int pos = atomicAdd(&cur[d >> BSH], 1);
            uint2 v; v.x = (unsigned)s; v.y = (unsigned)d;
            binned[pos] = v;
        }
    }
}

// Phase 4: one block per bucket (512 nodes). Count degrees, local scan,
// write cnt/rowptr/dinv, then fill esrc -- all cursors/counts in LDS.
__global__ __launch_bounds__(256) void bucket_build_kernel(const uint2* __restrict__ binned,
                                                           const int* __restrict__ Hscan,
                                                           int* __restrict__ cnt,
                                                           int* __restrict__ rowptr,
                                                           float* __restrict__ dinv,
                                                           int* __restrict__ esrc,
                                                           int e, int G, int n) {
    __shared__ int lcnt[512], lexc[512], ssum[256];
    const int t = threadIdx.x;
    const int b = blockIdx.x;
    const int start = Hscan[b * G];
    const int end = (b == BKT - 1) ? e : Hscan[(b + 1) * G];

    lcnt[t] = 0; lcnt[t + 256] = 0;
    __syncthreads();
    for (int i = start + t; i < end; i += 256)
        atomicAdd(&lcnt[binned[i].y & 511], 1);
    __syncthreads();

    int a0 = lcnt[2 * t], a1 = lcnt[2 * t + 1];
    ssum[t] = a0 + a1;
    __syncthreads();
    for (int off = 1; off < 256; off <<= 1) {
        int v = (t >= off) ? ssum[t - off] : 0;
        __syncthreads();
        ssum[t] += v;
        __syncthreads();
    }
    int excl = (t == 0) ? 0 : ssum[t - 1];
    lexc[2 * t] = excl;
    lexc[2 * t + 1] = excl + a0;
    __syncthreads();

    int nodebase = b << BSH;
#pragma unroll
    for (int j2 = 0; j2 < 2; j2++) {
        int j = 2 * t + j2;
        int node = nodebase + j;
        if (node < n) {
            int c = lcnt[j];
            cnt[node] = c;
            rowptr[node] = start + lexc[j];
            dinv[node] = rsqrtf((float)(c + 1));
        }
    }
    __syncthreads();

    for (int i = start + t; i < end; i += 256) {
        uint2 ed = binned[i];
        int pos = start + atomicAdd(&lexc[ed.y & 511], 1);
        esrc[pos] = (int)ed.x;
    }
}

// ---- scan helpers for H (bucket-major (bucket,block) histogram) ----

__global__ void blocksum_kernel(const int* __restrict__ in, int* __restrict__ bsum, int n) {
    int t = threadIdx.x;
    int base = blockIdx.x * 1024 + t * 4;
    int s = 0;
    if (base + 3 < n) {
        int4 v = *(const int4*)&in[base];
        s = v.x + v.y + v.z + v.w;
    } else {
        for (int j = 0; j < 4; j++) if (base + j < n) s += in[base + j];
    }
    __shared__ int ls[256];
    ls[t] = s;
    __syncthreads();
    for (int off = 128; off > 0; off >>= 1) {
        if (t < off) ls[t] += ls[t + off];
        __syncthreads();
    }
    if (t == 0) bsum[blockIdx.x] = ls[0];
}

__global__ void scan_bsum_kernel(int* __restrict__ bsum, int nb) {
    int t = threadIdx.x;
    __shared__ int ls[256];
    int v = (t < nb) ? bsum[t] : 0;
    ls[t] = v;
    __syncthreads();
    for (int off = 1; off < 256; off <<= 1) {
        int p = (t >= off) ? ls[t - off] : 0;
        __syncthreads();
        ls[t] += p;
        __syncthreads();
    }
    if (t < nb) bsum[t] = ls[t] - v;   // inclusive -> exclusive
}

__global__ void scan_write1_kernel(const int* __restrict__ in, const int* __restrict__ bsum,
                                   int* __restrict__ out, int n) {
    int t = threadIdx.x;
    int base = blockIdx.x * 1024 + t * 4;
    int v[4];
    int s = 0;
    if (base + 3 < n) {
        int4 q = *(const int4*)&in[base];
        v[0] = q.x; v[1] = q.y; v[2] = q.z; v[3] = q.w;
        s = q.x + q.y + q.z + q.w;
    } else {
        for (int j = 0; j < 4; j++) { v[j] = (base + j < n) ? in[base + j] : 0; s += v[j]; }
    }
    __shared__ int ls[256];
    ls[t] = s;
    __syncthreads();
    for (int off = 1; off < 256; off <<= 1) {
        int p = (t >= off) ? ls[t - off] : 0;
        __syncthreads();
        ls[t] += p;
        __syncthreads();
    }
    int run = bsum[blockIdx.x] + ls[t] - s;
    if (base + 3 < n) {
        int4 r; r.x = run; r.y = run + v[0]; r.z = run + v[0] + v[1]; r.w = run + v[0] + v[1] + v[2];
        *(int4*)&out[base] = r;
    } else {
        for (int j = 0; j < 4; j++) {
            if (base + j < n) out[base + j] = run;
            run += v[j];
        }
    }
}

// ---------------- W fragment prep: W[128][OUTC] fp32 -> hi/lo bf16 MFMA B-fragments ----
// Layout: slot = (ct*4 + kc)*64 + lane; each slot holds 8 bf16 (16B):
//   element j: W[kc*32 + (lane>>4)*8 + j][ct*16 + (lane&15)]
// hi = bf16_rne(w), lo = bf16_rne(w - hi)  (split-precision operands).
// All three weight matrices prepped in ONE launch (20 blocks).

__device__ __forceinline__ void wprep_one(const float* __restrict__ W,
                                          uint4* __restrict__ whi, uint4* __restrict__ wlo,
                                          int slot, int OUTC) {
    int l  = slot & 63;
    int kc = (slot >> 6) & 3;
    int ct = slot >> 8;
    int c  = ct * 16 + (l & 15);
    int k0 = kc * 32 + (l >> 4) * 8;
    unsigned hi[4], lo[4];
#pragma unroll
    for (int jj = 0; jj < 4; jj++) {
        float v0 = W[(size_t)(k0 + 2 * jj) * OUTC + c];
        float v1 = W[(size_t)(k0 + 2 * jj + 1) * OUTC + c];
        unsigned h0 = f32_to_bf16_rne(v0), h1 = f32_to_bf16_rne(v1);
        float l0 = v0 - __uint_as_float(h0 << 16);
        float l1 = v1 - __uint_as_float(h1 << 16);
        hi[jj] = h0 | (h1 << 16);
        lo[jj] = pack_bf16x2(l0, l1);
    }
    uint4 uh; uh.x = hi[0]; uh.y = hi[1]; uh.z = hi[2]; uh.w = hi[3];
    uint4 ul; ul.x = lo[0]; ul.y = lo[1]; ul.z = lo[2]; ul.w = lo[3];
    whi[slot] = uh;
    wlo[slot] = ul;
}

__global__ void wprep_all_kernel(const float* __restrict__ W1, uint4* w1hi, uint4* w1lo,
                                 const float* __restrict__ W2, uint4* w2hi, uint4* w2lo,
                                 const float* __restrict__ W3, uint4* w3hi, uint4* w3lo) {
    int id = blockIdx.x * 256 + threadIdx.x;
    if (id < 2048)       wprep_one(W1, w1hi, w1lo, id, 128);
    else if (id < 4096)  wprep_one(W2, w2hi, w2lo, id - 2048, 128);
    else if (id < 5120)  wprep_one(W3, w3hi, w3lo, id - 4096, 64);
}

// ---------------- GEMM via bf16 MFMA (fp32-equivalent via hi/lo split) ----------------
// Y[n,OUTC](bf16, pre-scaled by dinv[row]) = dinv[r] * act(X[n,128]) @ W[128,OUTC]
// act = BN(scale,shift)+ReLU when scale!=nullptr, else identity.
// Per block: 64 rows x OUTC cols. 4 waves; wave w owns col-tiles {w*CTW .. }.
// Operands SWAPPED in mfma (W-frag as A, X-frag as B) so D is row-major per
// lane: lane holds 4 consecutive output cols of one row -> uint2 store.

template <int OUTC>
__global__ __launch_bounds__(256) void gemm_kernel(const float* __restrict__ X,
                                                   const uint4* __restrict__ whi,
                                                   const uint4* __restrict__ wlo,
                                                   const float* __restrict__ scale,
                                                   const float* __restrict__ shift,
                                                   const float* __restrict__ dinv,
                                                   unsigned int* __restrict__ Y, int n) {
    constexpr int NCT = OUTC / 16;
    constexpr int CTW = NCT / 4;   // col-tiles per wave (2 for OUTC=128, 1 for 64)
    __shared__ __align__(16) unsigned short lAhi[64 * 128];  // 16 KB, XOR-swizzled
    __shared__ __align__(16) unsigned short lAlo[64 * 128];  // 16 KB
    __shared__ float ldv[64];
    const int t = threadIdx.x;
    const int base = blockIdx.x * 64;
    const int lane = t & 63;
    const int w = t >> 6;
    const bool bn = (scale != nullptr);

    if (t < 64) { int r = base + t; ldv[t] = (r < n) ? dinv[r] : 0.0f; }

    // B fragments (registers, whole kernel): CTW x 4 kc x {hi,lo}
    bf16x8 bhi[CTW][4], blo[CTW][4];
#pragma unroll
    for (int c = 0; c < CTW; c++) {
        int ct = w * CTW + c;
#pragma unroll
        for (int kc = 0; kc < 4; kc++) {
            int slot = (ct * 4 + kc) * 64 + lane;
            bhi[c][kc] = *reinterpret_cast<const bf16x8*>(whi + slot);
            blo[c][kc] = *reinterpret_cast<const bf16x8*>(wlo + slot);
        }
    }

    // Stage A: coalesced fp32 loads, fused BN+ReLU, hi/lo bf16 split, swizzled LDS.
    const int col4 = (t & 31) * 4;
    float4 sc4, sh4;
    if (bn) {
        sc4 = *(const float4*)&scale[col4];
        sh4 = *(const float4*)&shift[col4];
    }
#pragma unroll
    for (int i = 0; i < 8; i++) {
        int row = i * 8 + (t >> 5);
        int r = base + row;
        float4 xv = make_float4(0.f, 0.f, 0.f, 0.f);
        if (r < n) xv = *(const float4*)&X[(size_t)r * 128 + col4];
        if (bn) {
            xv.x = fmaxf(fmaf(xv.x, sc4.x, sh4.x), 0.0f);
            xv.y = fmaxf(fmaf(xv.y, sc4.y, sh4.y), 0.0f);
            xv.z = fmaxf(fmaf(xv.z, sc4.z, sh4.z), 0.0f);
            xv.w = fmaxf(fmaf(xv.w, sc4.w, sh4.w), 0.0f);
        }
        unsigned h0 = f32_to_bf16_rne(xv.x), h1 = f32_to_bf16_rne(xv.y);
        unsigned h2 = f32_to_bf16_rne(xv.z), h3 = f32_to_bf16_rne(xv.w);
        float l0 = xv.x - __uint_as_float(h0 << 16);
        float l1 = xv.y - __uint_as_float(h1 << 16);
        float l2 = xv.z - __uint_as_float(h2 << 16);
        float l3 = xv.w - __uint_as_float(h3 << 16);
        uint2 ph; ph.x = h0 | (h1 << 16); ph.y = h2 | (h3 << 16);
        uint2 pl; pl.x = pack_bf16x2(l0, l1); pl.y = pack_bf16x2(l2, l3);
        int off = row * 256 + ((col4 * 2) ^ ((row & 7) << 4));
        *(uint2*)((char*)lAhi + off) = ph;
        *(uint2*)((char*)lAlo + off) = pl;
    }
    __syncthreads();

    // Compute: 4 row-tiles of 16; per (rt,kc): 2 LDS frag reads + 3*CTW MFMAs.
    const int arow = lane & 15;
    const int kb16 = (lane >> 4) * 16;
#pragma unroll
    for (int rt = 0; rt < 4; rt++) {
        f32x4 acc[CTW];
#pragma unroll
        for (int c = 0; c < CTW; c++) acc[c] = (f32x4){0.f, 0.f, 0.f, 0.f};
        int row = rt * 16 + arow;
        int rb = row * 256;
        int sw = (row & 7) << 4;
#pragma unroll
        for (int kc = 0; kc < 4; kc++) {
            int off = rb + ((kc * 64 + kb16) ^ sw);
            bf16x8 ah = *(const bf16x8*)((const char*)lAhi + off);
            bf16x8 al = *(const bf16x8*)((const char*)lAlo + off);
#pragma unroll
            for (int c = 0; c < CTW; c++) {
                acc[c] = __builtin_amdgcn_mfma_f32_16x16x32_bf16(bhi[c][kc], ah, acc[c], 0, 0, 0);
                acc[c] = __builtin_amdgcn_mfma_f32_16x16x32_bf16(blo[c][kc], ah, acc[c], 0, 0, 0);
                acc[c] = __builtin_amdgcn_mfma_f32_16x16x32_bf16(bhi[c][kc], al, acc[c], 0, 0, 0);
            }
        }
        int r = base + row;
        if (r < n) {
            float dv = ldv[row];
#pragma unroll
            for (int c = 0; c < CTW; c++) {
                int ct = w * CTW + c;
                uint2 o;
                o.x = pack_bf16x2(acc[c][0] * dv, acc[c][1] * dv);
                o.y = pack_bf16x2(acc[c][2] * dv, acc[c][3] * dv);
                *(uint2*)&Y[(size_t)r * (OUTC / 2) + ct * 8 + (lane >> 4) * 2] = o;
            }
        }
    }
}

// ---------------- aggregation (128 cols): TWO nodes per wave + atomic-free BN partials ----
// xw rows are pre-scaled by dinv[src]. out[d] = dinv[d]*(sum xw'[s] + xw'[d]) + b.
// 32 lanes per node, uint2 (8B) gathers; 8-deep batch pipeline, clamped
// indices kill the tail. Epilogue (NO atomics -- R4's atomic version choked):
// per-block LDS slab [8][128] of h and h^2 (pure stores, disjoint addrs),
// one barrier, 8-way column sum, one coalesced 1KB store per block to
// bnpart[block][256]. Replaces the separate 51-MB bn_stats pass.

__global__ __launch_bounds__(256) void agg128_kernel(const unsigned int* __restrict__ xw,
                                                     const int* __restrict__ rowptr,
                                                     const int* __restrict__ cnt,
                                                     const int* __restrict__ esrc,
                                                     const float* __restrict__ dinv,
                                                     const float* __restrict__ bias,
                                                     float* __restrict__ out,
                                                     float* __restrict__ bnpart, int n) {
    __shared__ float lp[8][128];
    __shared__ float lq[8][128];

    const uint2* xw2 = (const uint2*)xw;
    int wid = (blockIdx.x * 256 + threadIdx.x) >> 6;   // wave index
    int lane = threadIdx.x & 63;
    int half = lane >> 5;
    int hl = lane & 31;
    int node = wid * 2 + half;
    bool ok = node < n;
    int nc = ok ? node : 0;

    float di = dinv[nc];
    int beg = rowptr[nc];
    int cv  = ok ? cnt[nc] : 0;
    int last = beg + cv - 1;
    int nb = (cv + 7) >> 3;

    uint2 ap = xw2[(size_t)nc * 32 + hl];
    float ax = bf16_lo(ap.x), ay = bf16_hi(ap.x);
    float az = bf16_lo(ap.y), aw = bf16_hi(ap.y);

    int s[8], sn[8];
    if (nb > 0) {
#pragma unroll
        for (int j = 0; j < 8; j++) {
            int idx = beg + j;
            s[j] = esrc[idx <= last ? idx : last];
        }
    }
    for (int b = 0; b < nb; b++) {
        int ebase = beg + b * 8;
        if (b + 1 < nb) {
#pragma unroll
            for (int j = 0; j < 8; j++) {
                int idx = ebase + 8 + j;
                sn[j] = esrc[idx <= last ? idx : last];
            }
        }
        uint2 v[8];
#pragma unroll
        for (int j = 0; j < 8; j++) v[j] = xw2[(size_t)s[j] * 32 + hl];
        int rem = last - ebase;   // valid j <= rem
#pragma unroll
        for (int j = 0; j < 8; j++) {
            float m = (j <= rem) ? 1.0f : 0.0f;
            ax = fmaf(m, bf16_lo(v[j].x), ax);
            ay = fmaf(m, bf16_hi(v[j].x), ay);
            az = fmaf(m, bf16_lo(v[j].y), az);
            aw = fmaf(m, bf16_hi(v[j].y), aw);
        }
        if (b + 1 < nb) {
#pragma unroll
            for (int j = 0; j < 8; j++) s[j] = sn[j];
        }
    }

    float4 o = make_float4(0.f, 0.f, 0.f, 0.f);
    if (ok) {
        float4 bv = ((const float4*)bias)[hl];
        o.x = fmaf(di, ax, bv.x);
        o.y = fmaf(di, ay, bv.y);
        o.z = fmaf(di, az, bv.z);
        o.w = fmaf(di, aw, bv.w);
        ((float4*)(out + (size_t)node * 128))[hl] = o;
    }

    // atomic-free BN partials (o == 0 for node >= n -> contributes nothing)
    int row8 = (threadIdx.x >> 6) * 2 + half;  // 0..7
    int c0 = hl * 4;
    lp[row8][c0 + 0] = o.x;  lq[row8][c0 + 0] = o.x * o.x;
    lp[row8][c0 + 1] = o.y;  lq[row8][c0 + 1] = o.y * o.y;
    lp[row8][c0 + 2] = o.z;  lq[row8][c0 + 2] = o.z * o.z;
    lp[row8][c0 + 3] = o.w;  lq[row8][c0 + 3] = o.w * o.w;
    __syncthreads();
    int c = threadIdx.x & 127;
    int which = threadIdx.x >> 7;
    float srd = 0.0f;
#pragma unroll
    for (int r = 0; r < 8; r++) srd += which ? lq[r][c] : lp[r][c];
    bnpart[(size_t)blockIdx.x * 256 + threadIdx.x] = srd;
}

// ---------------- aggregation (64-col output layer): TWO nodes per wave ----------------

__global__ __launch_bounds__(256) void agg64_kernel(const unsigned int* __restrict__ xw,
                                                    const int* __restrict__ rowptr,
                                                    const int* __restrict__ cnt,
                                                    const int* __restrict__ esrc,
                                                    const float* __restrict__ dinv,
                                                    const float* __restrict__ bias,
                                                    float* __restrict__ out, int n) {
    int wid = (blockIdx.x * 256 + threadIdx.x) >> 6;
    int lane = threadIdx.x & 63;
    int half = lane >> 5;
    int hl = lane & 31;
    int node = wid * 2 + half;
    bool ok = node < n;
    int nc = ok ? node : 0;

    float di = dinv[nc];
    int beg = rowptr[nc];
    int cv  = ok ? cnt[nc] : 0;
    int last = beg + cv - 1;
    int nb = (cv + 7) >> 3;

    unsigned int ap = xw[(size_t)nc * 32 + hl];
    float ax = bf16_lo(ap), ay = bf16_hi(ap);

    int s[8], sn[8];
    if (nb > 0) {
#pragma unroll
        for (int j = 0; j < 8; j++) {
            int idx = beg + j;
            s[j] = esrc[idx <= last ? idx : last];
        }
    }
    for (int b = 0; b < nb; b++) {
        int ebase = beg + b * 8;
        if (b + 1 < nb) {
#pragma unroll
            for (int j = 0; j < 8; j++) {
                int idx = ebase + 8 + j;
                sn[j] = esrc[idx <= last ? idx : last];
            }
        }
        unsigned int v[8];
#pragma unroll
        for (int j = 0; j < 8; j++) v[j] = xw[(size_t)s[j] * 32 + hl];
        int rem = last - ebase;
#pragma unroll
        for (int j = 0; j < 8; j++) {
            float m = (j <= rem) ? 1.0f : 0.0f;
            ax = fmaf(m, bf16_lo(v[j]), ax);
            ay = fmaf(m, bf16_hi(v[j]), ay);
        }
        if (b + 1 < nb) {
#pragma unroll
            for (int j = 0; j < 8; j++) s[j] = sn[j];
        }
    }
    if (ok) {
        float2 bv = ((const float2*)bias)[hl];
        float2 o;
        o.x = fmaf(di, ax, bv.x);
        o.y = fmaf(di, ay, bv.y);
        ((float2*)(out + (size_t)node * 64))[hl] = o;
    }
}

// ---------------- BN partial reduce (64 blocks, few atomics) + finalize ----------------

__global__ void bnred_partial_kernel(const float* __restrict__ part, float* __restrict__ sums,
                                     int nblk) {
    int t = threadIdx.x;
    float s = 0.0f;
    for (int r = blockIdx.x; r < nblk; r += gridDim.x)
        s += part[(size_t)r * 256 + t];
    atomicAdd(&sums[t], s);
}

__global__ void bn_finalize_kernel(const float* __restrict__ sums, const float* __restrict__ g,
                                   const float* __restrict__ be, float* __restrict__ scale,
                                   float* __restrict__ shift, int n) {
    int c = threadIdx.x;  // 128 threads
    float inv_n = 1.0f / (float)n;
    float mean = sums[c] * inv_n;
    float var = sums[128 + c] * inv_n - mean * mean;
    float rstd = rsqrtf(var + BN_EPS);
    float sc = rstd * g[c];
    scale[c] = sc;
    shift[c] = be[c] - mean * sc;
}

// ---------------- launch ----------------

extern "C" void kernel_launch(void* const* d_in, const int* in_sizes, int n_in,
                              void* d_out, int out_size, void* d_ws, size_t ws_size,
                              hipStream_t stream) {
    const float* x   = (const float*)d_in[0];
    const int*   ei  = (const int*)d_in[1];
    const float* W1  = (const float*)d_in[2];
    const float* b1  = (const float*)d_in[3];
    const float* g1  = (const float*)d_in[4];
    const float* be1 = (const float*)d_in[5];
    const float* W2  = (const float*)d_in[6];
    const float* b2  = (const float*)d_in[7];
    const float* g2  = (const float*)d_in[8];
    const float* be2 = (const float*)d_in[9];
    const float* W3  = (const float*)d_in[10];
    const float* b3  = (const float*)d_in[11];

    const int n = in_sizes[0] / 128;
    const int E = in_sizes[1] / 2;
    const int* srcv = ei;
    const int* dstv = ei + E;

    const int G = (E + CHUNK - 1) / CHUNK;      // hist/scatter blocks (196)
    const int HN = BKT * G;                      // H matrix elements (50176)
    const int NB = (n + 511) >> 9;               // used buckets (196)

    char* p = (char*)d_ws;
    auto carve = [&](size_t bytes) -> char* {
        char* q = p;
        p += (bytes + 255) & ~(size_t)255;
        return q;
    };
    int*   cnt    = (int*)carve((size_t)n * 4);
    int*   rowptr = (int*)carve((size_t)n * 4);
    float* dinv   = (float*)carve((size_t)n * 4);
    int*   esrc   = (int*)carve((size_t)E * 4);
    uint2* binned = (uint2*)carve((size_t)E * 8);   // dead after bucket_build; reused as bnpart
    int*   H      = (int*)carve((size_t)HN * 4);
    int*   Hscan  = (int*)carve((size_t)HN * 4);
    float* sums   = (float*)carve(512 * 4);          // [sum1|sq1|sum2|sq2]
    float* bnsc   = (float*)carve(512 * 4);          // [scale1|shift1|scale2|shift2]
    int*   bsum   = (int*)carve(1024 * 4);
    uint4* w1hi   = (uint4*)carve(2048 * 16); // W-frag arrays (hi/lo bf16)
    uint4* w1lo   = (uint4*)carve(2048 * 16);
    uint4* w2hi   = (uint4*)carve(2048 * 16);
    uint4* w2lo   = (uint4*)carve(2048 * 16);
    uint4* w3hi   = (uint4*)carve(1024 * 16);
    uint4* w3lo   = (uint4*)carve(1024 * 16);
    unsigned int* xwb = (unsigned int*)carve((size_t)n * 128 * 2);  // gemm out (bf16 packed, pre-scaled by dinv)
    float* bufB   = (float*)carve((size_t)n * 128 * 4);             // agg out (fp32)

    float* bnpart = (float*)binned;   // ab*256*4 = 12.8 MB <= E*8 = 12.8 MB (exact fit)

    hipMemsetAsync(sums, 0, 512 * 4, stream);

    int sbH = (HN + 1023) / 1024;    // 49 <= 256

    // W fragment prep, single launch (no deps; overlaps CSR build region)
    wprep_all_kernel<<<20, 256, 0, stream>>>(W1, w1hi, w1lo, W2, w2hi, w2lo, W3, w3hi, w3lo);

    // bucketed CSR build (single LDS-atomic build kernel; no global N-scan)
    hist_kernel<<<G, 256, 0, stream>>>(dstv, H, E, G);
    blocksum_kernel<<<sbH, 256, 0, stream>>>(H, bsum, HN);
    scan_bsum_kernel<<<1, 256, 0, stream>>>(bsum, sbH);
    scan_write1_kernel<<<sbH, 256, 0, stream>>>(H, bsum, Hscan, HN);
    bin_scatter_kernel<<<G, 256, 0, stream>>>(srcv, dstv, Hscan, binned, E, G);
    bucket_build_kernel<<<NB, 256, 0, stream>>>(binned, Hscan, cnt, rowptr, dinv, esrc, E, G, n);

    int gb = (n + 63) / 64;
    int ab = (n + 7) / 8;   // 2 nodes per wave, 4 waves per block

    // layer 1: gcn(x, W1) + b1  (agg epilogue writes per-block BN partials)
    gemm_kernel<128><<<gb, 256, 0, stream>>>(x, w1hi, w1lo, nullptr, nullptr, dinv, xwb, n);
    agg128_kernel<<<ab, 256, 0, stream>>>(xwb, rowptr, cnt, esrc, dinv, b1, bufB, bnpart, n);
    bnred_partial_kernel<<<64, 256, 0, stream>>>(bnpart, sums, ab);
    bn_finalize_kernel<<<1, 128, 0, stream>>>(sums, g1, be1, bnsc, bnsc + 128, n);

    // layer 2: gcn(relu(bn1(h)), W2) + b2   (bn1+relu fused into gemm staging)
    gemm_kernel<128><<<gb, 256, 0, stream>>>(bufB, w2hi, w2lo, bnsc, bnsc + 128, dinv, xwb, n);
    agg128_kernel<<<ab, 256, 0, stream>>>(xwb, rowptr, cnt, esrc, dinv, b2, bufB, bnpart, n);
    bnred_partial_kernel<<<64, 256, 0, stream>>>(bnpart, sums + 256, ab);
    bn_finalize_kernel<<<1, 128, 0, stream>>>(sums + 256, g2, be2, bnsc + 256, bnsc + 384, n);

    // layer 3: gcn(relu(bn2(h)), W3) + b3  -> d_out
    gemm_kernel<64><<<gb, 256, 0, stream>>>(bufB, w3hi, w3lo, bnsc + 256, bnsc + 384, dinv, xwb, n);
    agg64_kernel<<<ab, 256, 0, stream>>>(xwb, rowptr, cnt, esrc, dinv, b3, (float*)d_out, n);
}

// Round 7
// 445.662 us; speedup vs baseline: 1.3032x; 1.1326x over previous
//
#include <hip/hip_runtime.h>
#include <cstdint>
#include <cstddef>

#define BN_EPS 1e-5f
#define BKT 256        // buckets (dst>>9), 512 nodes each; 100000>>9 = 195 -> 196 used
#define BSH 9
#define CHUNK 8192     // edges per block in hist/scatter

typedef __attribute__((ext_vector_type(8))) short bf16x8;   // 8 bf16 = 4 VGPRs
typedef __attribute__((ext_vector_type(4))) float f32x4;    // MFMA acc

// ---- manual bf16 helpers (hip_bf16.h intrinsics unavailable in this ROCm) ----
__device__ __forceinline__ unsigned int f32_to_bf16_rne(float f) {
    unsigned int u = __float_as_uint(f);
    u += 0x7FFFu + ((u >> 16) & 1u);
    return u >> 16;
}
__device__ __forceinline__ unsigned int pack_bf16x2(float a, float b) {
    return f32_to_bf16_rne(a) | (f32_to_bf16_rne(b) << 16);
}
__device__ __forceinline__ float bf16_lo(unsigned int p) { return __uint_as_float(p << 16); }
__device__ __forceinline__ float bf16_hi(unsigned int p) { return __uint_as_float(p & 0xFFFF0000u); }

// ---------------- bucketed CSR build ----------------
__global__ void hist_kernel(const int* __restrict__ dst, int* __restrict__ H, int e, int G) {
    __shared__ int h[BKT];
    int t = threadIdx.x, g = blockIdx.x;
    h[t] = 0;
    __syncthreads();
    int base = g * CHUNK;
#pragma unroll
    for (int i = 0; i < CHUNK / 256; i++) {
        int idx = base + i * 256 + t;
        if (idx < e) atomicAdd(&h[dst[idx] >> BSH], 1);
    }
    __syncthreads();
    H[t * G + g] = h[t];
}

__global__ void bin_scatter_kernel(const int* __restrict__ src, const int* __restrict__ dst,
                                   const int* __restrict__ Hscan, uint2* __restrict__ binned,
                                   int e, int G) {
    __shared__ int cur[BKT];
    int t = threadIdx.x, g = blockIdx.x;
    cur[t] = Hscan[t * G + g];
    __syncthreads();
    int base = g * CHUNK;
#pragma unroll
    for (int i = 0; i < CHUNK / 256; i++) {
        int idx = base + i * 256 + t;
        if (idx < e) {
            int s = src[idx], d = dst[idx];
            int pos = atomicAdd(&cur[d >> BSH], 1);
            uint2 v; v.x = (unsigned)s; v.y = (unsigned)d;
            binned[pos] = v;
        }
    }
}

__global__ __launch_bounds__(256) void bucket_build_kernel(const uint2* __restrict__ binned,
                                                           const int* __restrict__ Hscan,
                                                           int* __restrict__ cnt,
                                                           int* __restrict__ rowptr,
                                                           float* __restrict__ dinv,
                                                           int* __restrict__ esrc,
                                                           int e, int G, int n) {
    __shared__ int lcnt[512], lexc[512], ssum[256];
    const int t = threadIdx.x;
    const int b = blockIdx.x;
    const int start = Hscan[b * G];
    const int end = (b == BKT - 1) ? e : Hscan[(b + 1) * G];

    lcnt[t] = 0; lcnt[t + 256] = 0;
    __syncthreads();
    for (int i = start + t; i < end; i += 256)
        atomicAdd(&lcnt[binned[i].y & 511], 1);
    __syncthreads();

    int a0 = lcnt[2 * t], a1 = lcnt[2 * t + 1];
    ssum[t] = a0 + a1;
    __syncthreads();
    for (int off = 1; off < 256; off <<= 1) {
        int v = (t >= off) ? ssum[t - off] : 0;
        __syncthreads();
        ssum[t] += v;
        __syncthreads();
    }
    int excl = (t == 0) ? 0 : ssum[t - 1];
    lexc[2 * t] = excl;
    lexc[2 * t + 1] = excl + a0;
    __syncthreads();

    int nodebase = b << BSH;
#pragma unroll
    for (int j2 = 0; j2 < 2; j2++) {
        int j = 2 * t + j2;
        int node = nodebase + j;
        if (node < n) {
            int c = lcnt[j];
            cnt[node] = c;
            rowptr[node] = start + lexc[j];
            dinv[node] = rsqrtf((float)(c + 1));
        }
    }
    __syncthreads();

    for (int i = start + t; i < end; i += 256) {
        uint2 ed = binned[i];
        int pos = start + atomicAdd(&lexc[ed.y & 511], 1);
        esrc[pos] = (int)ed.x;
    }
}

// ---- scan helpers for H (bucket-major (bucket,block) histogram) ----

__global__ void blocksum_kernel(const int* __restrict__ in, int* __restrict__ bsum, int n) {
    int t = threadIdx.x;
    int base = blockIdx.x * 1024 + t * 4;
    int s = 0;
    if (base + 3 < n) {
        int4 v = *(const int4*)&in[base];
        s = v.x + v.y + v.z + v.w;
    } else {
        for (int j = 0; j < 4; j++) if (base + j < n) s += in[base + j];
    }
    __shared__ int ls[256];
    ls[t] = s;
    __syncthreads();
    for (int off = 128; off > 0; off >>= 1) {
        if (t < off) ls[t] += ls[t + off];
        __syncthreads();
    }
    if (t == 0) bsum[blockIdx.x] = ls[0];
}

__global__ void scan_bsum_kernel(int* __restrict__ bsum, int nb) {
    int t = threadIdx.x;
    __shared__ int ls[256];
    int v = (t < nb) ? bsum[t] : 0;
    ls[t] = v;
    __syncthreads();
    for (int off = 1; off < 256; off <<= 1) {
        int p = (t >= off) ? ls[t - off] : 0;
        __syncthreads();
        ls[t] += p;
        __syncthreads();
    }
    if (t < nb) bsum[t] = ls[t] - v;   // inclusive -> exclusive
}

__global__ void scan_write1_kernel(const int* __restrict__ in, const int* __restrict__ bsum,
                                   int* __restrict__ out, int n) {
    int t = threadIdx.x;
    int base = blockIdx.x * 1024 + t * 4;
    int v[4];
    int s = 0;
    if (base + 3 < n) {
        int4 q = *(const int4*)&in[base];
        v[0] = q.x; v[1] = q.y; v[2] = q.z; v[3] = q.w;
        s = q.x + q.y + q.z + q.w;
    } else {
        for (int j = 0; j < 4; j++) { v[j] = (base + j < n) ? in[base + j] : 0; s += v[j]; }
    }
    __shared__ int ls[256];
    ls[t] = s;
    __syncthreads();
    for (int off = 1; off < 256; off <<= 1) {
        int p = (t >= off) ? ls[t - off] : 0;
        __syncthreads();
        ls[t] += p;
        __syncthreads();
    }
    int run = bsum[blockIdx.x] + ls[t] - s;
    if (base + 3 < n) {
        int4 r; r.x = run; r.y = run + v[0]; r.z = run + v[0] + v[1]; r.w = run + v[0] + v[1] + v[2];
        *(int4*)&out[base] = r;
    } else {
        for (int j = 0; j < 4; j++) {
            if (base + j < n) out[base + j] = run;
            run += v[j];
        }
    }
}

// ---------------- W fragment prep (hi/lo bf16 split), single launch ----------------

__device__ __forceinline__ void wprep_one(const float* __restrict__ W,
                                          uint4* __restrict__ whi, uint4* __restrict__ wlo,
                                          int slot, int OUTC) {
    int l  = slot & 63;
    int kc = (slot >> 6) & 3;
    int ct = slot >> 8;
    int c  = ct * 16 + (l & 15);
    int k0 = kc * 32 + (l >> 4) * 8;
    unsigned hi[4], lo[4];
#pragma unroll
    for (int jj = 0; jj < 4; jj++) {
        float v0 = W[(size_t)(k0 + 2 * jj) * OUTC + c];
        float v1 = W[(size_t)(k0 + 2 * jj + 1) * OUTC + c];
        unsigned h0 = f32_to_bf16_rne(v0), h1 = f32_to_bf16_rne(v1);
        float l0 = v0 - __uint_as_float(h0 << 16);
        float l1 = v1 - __uint_as_float(h1 << 16);
        hi[jj] = h0 | (h1 << 16);
        lo[jj] = pack_bf16x2(l0, l1);
    }
    uint4 uh; uh.x = hi[0]; uh.y = hi[1]; uh.z = hi[2]; uh.w = hi[3];
    uint4 ul; ul.x = lo[0]; ul.y = lo[1]; ul.z = lo[2]; ul.w = lo[3];
    whi[slot] = uh;
    wlo[slot] = ul;
}

__global__ void wprep_all_kernel(const float* __restrict__ W1, uint4* w1hi, uint4* w1lo,
                                 const float* __restrict__ W2, uint4* w2hi, uint4* w2lo,
                                 const float* __restrict__ W3, uint4* w3hi, uint4* w3lo) {
    int id = blockIdx.x * 256 + threadIdx.x;
    if (id < 2048)       wprep_one(W1, w1hi, w1lo, id, 128);
    else if (id < 4096)  wprep_one(W2, w2hi, w2lo, id - 2048, 128);
    else if (id < 5120)  wprep_one(W3, w3hi, w3lo, id - 4096, 64);
}

// ---------------- GEMM via bf16 MFMA (fp32-equivalent via hi/lo split) ----------------
// SLAB=true: write output TILE-MAJOR xw[slab(=ct)][node][16 cols] so that the
// slabbed aggregation's per-XCD gather footprint (n*32B = 3.2 MB) is cacheline-
// pure and fits the 4 MiB per-XCD L2. SLAB=false: row-major (layer 3 / agg64).

template <int OUTC, bool SLAB>
__global__ __launch_bounds__(256) void gemm_kernel(const float* __restrict__ X,
                                                   const uint4* __restrict__ whi,
                                                   const uint4* __restrict__ wlo,
                                                   const float* __restrict__ scale,
                                                   const float* __restrict__ shift,
                                                   const float* __restrict__ dinv,
                                                   unsigned int* __restrict__ Y, int n) {
    constexpr int NCT = OUTC / 16;
    constexpr int CTW = NCT / 4;   // col-tiles per wave (2 for OUTC=128, 1 for 64)
    __shared__ __align__(16) unsigned short lAhi[64 * 128];  // 16 KB, XOR-swizzled
    __shared__ __align__(16) unsigned short lAlo[64 * 128];  // 16 KB
    __shared__ float ldv[64];
    const int t = threadIdx.x;
    const int base = blockIdx.x * 64;
    const int lane = t & 63;
    const int w = t >> 6;
    const bool bn = (scale != nullptr);

    if (t < 64) { int r = base + t; ldv[t] = (r < n) ? dinv[r] : 0.0f; }

    bf16x8 bhi[CTW][4], blo[CTW][4];
#pragma unroll
    for (int c = 0; c < CTW; c++) {
        int ct = w * CTW + c;
#pragma unroll
        for (int kc = 0; kc < 4; kc++) {
            int slot = (ct * 4 + kc) * 64 + lane;
            bhi[c][kc] = *reinterpret_cast<const bf16x8*>(whi + slot);
            blo[c][kc] = *reinterpret_cast<const bf16x8*>(wlo + slot);
        }
    }

    const int col4 = (t & 31) * 4;
    float4 sc4, sh4;
    if (bn) {
        sc4 = *(const float4*)&scale[col4];
        sh4 = *(const float4*)&shift[col4];
    }
#pragma unroll
    for (int i = 0; i < 8; i++) {
        int row = i * 8 + (t >> 5);
        int r = base + row;
        float4 xv = make_float4(0.f, 0.f, 0.f, 0.f);
        if (r < n) xv = *(const float4*)&X[(size_t)r * 128 + col4];
        if (bn) {
            xv.x = fmaxf(fmaf(xv.x, sc4.x, sh4.x), 0.0f);
            xv.y = fmaxf(fmaf(xv.y, sc4.y, sh4.y), 0.0f);
            xv.z = fmaxf(fmaf(xv.z, sc4.z, sh4.z), 0.0f);
            xv.w = fmaxf(fmaf(xv.w, sc4.w, sh4.w), 0.0f);
        }
        unsigned h0 = f32_to_bf16_rne(xv.x), h1 = f32_to_bf16_rne(xv.y);
        unsigned h2 = f32_to_bf16_rne(xv.z), h3 = f32_to_bf16_rne(xv.w);
        float l0 = xv.x - __uint_as_float(h0 << 16);
        float l1 = xv.y - __uint_as_float(h1 << 16);
        float l2 = xv.z - __uint_as_float(h2 << 16);
        float l3 = xv.w - __uint_as_float(h3 << 16);
        uint2 ph; ph.x = h0 | (h1 << 16); ph.y = h2 | (h3 << 16);
        uint2 pl; pl.x = pack_bf16x2(l0, l1); pl.y = pack_bf16x2(l2, l3);
        int off = row * 256 + ((col4 * 2) ^ ((row & 7) << 4));
        *(uint2*)((char*)lAhi + off) = ph;
        *(uint2*)((char*)lAlo + off) = pl;
    }
    __syncthreads();

    const int arow = lane & 15;
    const int kb16 = (lane >> 4) * 16;
#pragma unroll
    for (int rt = 0; rt < 4; rt++) {
        f32x4 acc[CTW];
#pragma unroll
        for (int c = 0; c < CTW; c++) acc[c] = (f32x4){0.f, 0.f, 0.f, 0.f};
        int row = rt * 16 + arow;
        int rb = row * 256;
        int sw = (row & 7) << 4;
#pragma unroll
        for (int kc = 0; kc < 4; kc++) {
            int off = rb + ((kc * 64 + kb16) ^ sw);
            bf16x8 ah = *(const bf16x8*)((const char*)lAhi + off);
            bf16x8 al = *(const bf16x8*)((const char*)lAlo + off);
#pragma unroll
            for (int c = 0; c < CTW; c++) {
                acc[c] = __builtin_amdgcn_mfma_f32_16x16x32_bf16(bhi[c][kc], ah, acc[c], 0, 0, 0);
                acc[c] = __builtin_amdgcn_mfma_f32_16x16x32_bf16(blo[c][kc], ah, acc[c], 0, 0, 0);
                acc[c] = __builtin_amdgcn_mfma_f32_16x16x32_bf16(bhi[c][kc], al, acc[c], 0, 0, 0);
            }
        }
        int r = base + row;
        if (r < n) {
            float dv = ldv[row];
#pragma unroll
            for (int c = 0; c < CTW; c++) {
                int ct = w * CTW + c;
                uint2 o;
                o.x = pack_bf16x2(acc[c][0] * dv, acc[c][1] * dv);
                o.y = pack_bf16x2(acc[c][2] * dv, acc[c][3] * dv);
                if constexpr (SLAB)
                    *(uint2*)&Y[(size_t)ct * n * 8 + (size_t)r * 8 + (lane >> 4) * 2] = o;
                else
                    *(uint2*)&Y[(size_t)r * (OUTC / 2) + ct * 8 + (lane >> 4) * 2] = o;
            }
        }
    }
}

// ---------------- slabbed aggregation (128 cols, 8 XCD column-slabs) ----------------
// xw is TILE-MAJOR [slab][node][16 cols] (32B/node/slab, cacheline-pure).
// slab = blockIdx.x & 7 -> (empirical) all blocks of one slab land on one XCD,
// whose gather footprint n*32B = 3.2 MB fits the 4 MiB L2. Wave = 16 node-slots
// x 4 lanes; 8-deep clamped batch pipeline as before. Atomic-free BN partials:
// 32 floats per block (16 sum + 16 sumsq for this slab's cols).

__global__ __launch_bounds__(256) void agg128s_kernel(const unsigned int* __restrict__ xw,
                                                      const int* __restrict__ rowptr,
                                                      const int* __restrict__ cnt,
                                                      const int* __restrict__ esrc,
                                                      const float* __restrict__ dinv,
                                                      const float* __restrict__ bias,
                                                      float* __restrict__ out,
                                                      float* __restrict__ bnpart, int n) {
    __shared__ float lp[64][16], lq[64][16];
    __shared__ float lr[2][16][8];

    const uint2* xw2 = (const uint2*)xw;
    const int slab = blockIdx.x & 7;
    const int grp  = blockIdx.x >> 3;
    const int t = threadIdx.x;
    const int w = t >> 6;
    const int lane = t & 63;
    const int slot = lane >> 2;     // 0..15
    const int sub  = lane & 3;      // 0..3 (uint2 within 32B node-slab row)
    const int lnode = w * 16 + slot;   // 0..63
    const int node = grp * 64 + lnode;
    bool ok = node < n;
    int nc = ok ? node : 0;

    float di = dinv[nc];
    int beg = rowptr[nc];
    int cv  = ok ? cnt[nc] : 0;
    int last = beg + cv - 1;
    int nb = (cv + 7) >> 3;

    const size_t sbase = (size_t)slab * n * 4;   // uint2 per slab = n*4
    uint2 ap = xw2[sbase + (size_t)nc * 4 + sub];
    float ax = bf16_lo(ap.x), ay = bf16_hi(ap.x);
    float az = bf16_lo(ap.y), aw = bf16_hi(ap.y);

    int s[8], sn[8];
    if (nb > 0) {
#pragma unroll
        for (int j = 0; j < 8; j++) {
            int idx = beg + j;
            s[j] = esrc[idx <= last ? idx : last];
        }
    }
    for (int b = 0; b < nb; b++) {
        int ebase = beg + b * 8;
        if (b + 1 < nb) {
#pragma unroll
            for (int j = 0; j < 8; j++) {
                int idx = ebase + 8 + j;
                sn[j] = esrc[idx <= last ? idx : last];
            }
        }
        uint2 v[8];
#pragma unroll
        for (int j = 0; j < 8; j++) v[j] = xw2[sbase + (size_t)s[j] * 4 + sub];
        int rem = last - ebase;   // valid j <= rem
#pragma unroll
        for (int j = 0; j < 8; j++) {
            float m = (j <= rem) ? 1.0f : 0.0f;
            ax = fmaf(m, bf16_lo(v[j].x), ax);
            ay = fmaf(m, bf16_hi(v[j].x), ay);
            az = fmaf(m, bf16_lo(v[j].y), az);
            aw = fmaf(m, bf16_hi(v[j].y), aw);
        }
        if (b + 1 < nb) {
#pragma unroll
            for (int j = 0; j < 8; j++) s[j] = sn[j];
        }
    }

    float4 o = make_float4(0.f, 0.f, 0.f, 0.f);
    if (ok) {
        float4 bv = ((const float4*)bias)[slab * 4 + sub];
        o.x = fmaf(di, ax, bv.x);
        o.y = fmaf(di, ay, bv.y);
        o.z = fmaf(di, az, bv.z);
        o.w = fmaf(di, aw, bv.w);
        *(float4*)(out + (size_t)node * 128 + slab * 16 + sub * 4) = o;
    }

    // atomic-free BN partials for this slab's 16 columns
    int c0 = sub * 4;
    lp[lnode][c0 + 0] = o.x;  lq[lnode][c0 + 0] = o.x * o.x;
    lp[lnode][c0 + 1] = o.y;  lq[lnode][c0 + 1] = o.y * o.y;
    lp[lnode][c0 + 2] = o.z;  lq[lnode][c0 + 2] = o.z * o.z;
    lp[lnode][c0 + 3] = o.w;  lq[lnode][c0 + 3] = o.w * o.w;
    __syncthreads();
    {
        int col = t & 15;
        int which = (t >> 4) & 1;
        int chunk = t >> 5;             // 0..7
        float srd = 0.0f;
#pragma unroll
        for (int r = 0; r < 8; r++) {
            int rr = chunk * 8 + r;
            srd += which ? lq[rr][col] : lp[rr][col];
        }
        lr[which][col][chunk] = srd;
    }
    __syncthreads();
    if (t < 32) {
        int which = t >> 4;
        int col = t & 15;
        float srd = 0.0f;
#pragma unroll
        for (int c = 0; c < 8; c++) srd += lr[which][col][c];
        bnpart[(size_t)blockIdx.x * 32 + which * 16 + col] = srd;
    }
}

// ---------------- aggregation (64-col output layer): TWO nodes per wave ----------------

__global__ __launch_bounds__(256) void agg64_kernel(const unsigned int* __restrict__ xw,
                                                    const int* __restrict__ rowptr,
                                                    const int* __restrict__ cnt,
                                                    const int* __restrict__ esrc,
                                                    const float* __restrict__ dinv,
                                                    const float* __restrict__ bias,
                                                    float* __restrict__ out, int n) {
    int wid = (blockIdx.x * 256 + threadIdx.x) >> 6;
    int lane = threadIdx.x & 63;
    int half = lane >> 5;
    int hl = lane & 31;
    int node = wid * 2 + half;
    bool ok = node < n;
    int nc = ok ? node : 0;

    float di = dinv[nc];
    int beg = rowptr[nc];
    int cv  = ok ? cnt[nc] : 0;
    int last = beg + cv - 1;
    int nb = (cv + 7) >> 3;

    unsigned int ap = xw[(size_t)nc * 32 + hl];
    float ax = bf16_lo(ap), ay = bf16_hi(ap);

    int s[8], sn[8];
    if (nb > 0) {
#pragma unroll
        for (int j = 0; j < 8; j++) {
            int idx = beg + j;
            s[j] = esrc[idx <= last ? idx : last];
        }
    }
    for (int b = 0; b < nb; b++) {
        int ebase = beg + b * 8;
        if (b + 1 < nb) {
#pragma unroll
            for (int j = 0; j < 8; j++) {
                int idx = ebase + 8 + j;
                sn[j] = esrc[idx <= last ? idx : last];
            }
        }
        unsigned int v[8];
#pragma unroll
        for (int j = 0; j < 8; j++) v[j] = xw[(size_t)s[j] * 32 + hl];
        int rem = last - ebase;
#pragma unroll
        for (int j = 0; j < 8; j++) {
            float m = (j <= rem) ? 1.0f : 0.0f;
            ax = fmaf(m, bf16_lo(v[j]), ax);
            ay = fmaf(m, bf16_hi(v[j]), ay);
        }
        if (b + 1 < nb) {
#pragma unroll
            for (int j = 0; j < 8; j++) s[j] = sn[j];
        }
    }
    if (ok) {
        float2 bv = ((const float2*)bias)[hl];
        float2 o;
        o.x = fmaf(di, ax, bv.x);
        o.y = fmaf(di, ay, bv.y);
        ((float2*)(out + (size_t)node * 64))[hl] = o;
    }
}

// ---------------- BN partial reduce (slab layout) + finalize ----------------

__global__ void bnred_slab_kernel(const float* __restrict__ part, float* __restrict__ sums,
                                  int ngrp) {
    int t = threadIdx.x;   // 256
    int which = t >> 7;    // 0 = sum, 1 = sumsq
    int c = t & 127;       // global channel
    int slab = c >> 4, lcol = c & 15;
    float s = 0.0f;
    for (int k = blockIdx.x; k < ngrp; k += gridDim.x)
        s += part[(size_t)(k * 8 + slab) * 32 + which * 16 + lcol];
    atomicAdd(&sums[which * 128 + c], s);
}

__global__ void bn_finalize_kernel(const float* __restrict__ sums, const float* __restrict__ g,
                                   const float* __restrict__ be, float* __restrict__ scale,
                                   float* __restrict__ shift, int n) {
    int c = threadIdx.x;  // 128 threads
    float inv_n = 1.0f / (float)n;
    float mean = sums[c] * inv_n;
    float var = sums[128 + c] * inv_n - mean * mean;
    float rstd = rsqrtf(var + BN_EPS);
    float sc = rstd * g[c];
    scale[c] = sc;
    shift[c] = be[c] - mean * sc;
}

// ---------------- launch ----------------

extern "C" void kernel_launch(void* const* d_in, const int* in_sizes, int n_in,
                              void* d_out, int out_size, void* d_ws, size_t ws_size,
                              hipStream_t stream) {
    const float* x   = (const float*)d_in[0];
    const int*   ei  = (const int*)d_in[1];
    const float* W1  = (const float*)d_in[2];
    const float* b1  = (const float*)d_in[3];
    const float* g1  = (const float*)d_in[4];
    const float* be1 = (const float*)d_in[5];
    const float* W2  = (const float*)d_in[6];
    const float* b2  = (const float*)d_in[7];
    const float* g2  = (const float*)d_in[8];
    const float* be2 = (const float*)d_in[9];
    const float* W3  = (const float*)d_in[10];
    const float* b3  = (const float*)d_in[11];

    const int n = in_sizes[0] / 128;
    const int E = in_sizes[1] / 2;
    const int* srcv = ei;
    const int* dstv = ei + E;

    const int G = (E + CHUNK - 1) / CHUNK;      // hist/scatter blocks (196)
    const int HN = BKT * G;                      // H matrix elements (50176)
    const int NB = (n + 511) >> 9;               // used buckets (196)

    char* p = (char*)d_ws;
    auto carve = [&](size_t bytes) -> char* {
        char* q = p;
        p += (bytes + 255) & ~(size_t)255;
        return q;
    };
    int*   cnt    = (int*)carve((size_t)n * 4);
    int*   rowptr = (int*)carve((size_t)n * 4);
    float* dinv   = (float*)carve((size_t)n * 4);
    int*   esrc   = (int*)carve((size_t)E * 4);
    uint2* binned = (uint2*)carve((size_t)E * 8);   // dead after bucket_build; reused as bnpart
    int*   H      = (int*)carve((size_t)HN * 4);
    int*   Hscan  = (int*)carve((size_t)HN * 4);
    float* sums   = (float*)carve(512 * 4);          // [sum1|sq1|sum2|sq2]
    float* bnsc   = (float*)carve(512 * 4);          // [scale1|shift1|scale2|shift2]
    int*   bsum   = (int*)carve(1024 * 4);
    uint4* w1hi   = (uint4*)carve(2048 * 16); // W-frag arrays (hi/lo bf16)
    uint4* w1lo   = (uint4*)carve(2048 * 16);
    uint4* w2hi   = (uint4*)carve(2048 * 16);
    uint4* w2lo   = (uint4*)carve(2048 * 16);
    uint4* w3hi   = (uint4*)carve(1024 * 16);
    uint4* w3lo   = (uint4*)carve(1024 * 16);
    unsigned int* xwb = (unsigned int*)carve((size_t)n * 128 * 2);  // gemm out (bf16, tile-major for 128)
    float* bufB   = (float*)carve((size_t)n * 128 * 4);             // agg out (fp32)

    float* bnpart = (float*)binned;   // ngrp*8 blocks * 32 floats = 1.6 MB <= E*8

    hipMemsetAsync(sums, 0, 512 * 4, stream);

    int sbH = (HN + 1023) / 1024;    // 49 <= 256

    // W fragment prep, single launch (no deps; overlaps CSR build region)
    wprep_all_kernel<<<20, 256, 0, stream>>>(W1, w1hi, w1lo, W2, w2hi, w2lo, W3, w3hi, w3lo);

    // bucketed CSR build
    hist_kernel<<<G, 256, 0, stream>>>(dstv, H, E, G);
    blocksum_kernel<<<sbH, 256, 0, stream>>>(H, bsum, HN);
    scan_bsum_kernel<<<1, 256, 0, stream>>>(bsum, sbH);
    scan_write1_kernel<<<sbH, 256, 0, stream>>>(H, bsum, Hscan, HN);
    bin_scatter_kernel<<<G, 256, 0, stream>>>(srcv, dstv, Hscan, binned, E, G);
    bucket_build_kernel<<<NB, 256, 0, stream>>>(binned, Hscan, cnt, rowptr, dinv, esrc, E, G, n);

    int gb = (n + 63) / 64;
    int ngrp = (n + 63) / 64;       // 64 nodes per slab-block
    int ab = (n + 7) / 8;           // agg64: 2 nodes per wave

    // layer 1: gcn(x, W1) + b1  (slabbed agg; epilogue writes BN partials)
    gemm_kernel<128, true><<<gb, 256, 0, stream>>>(x, w1hi, w1lo, nullptr, nullptr, dinv, xwb, n);
    agg128s_kernel<<<ngrp * 8, 256, 0, stream>>>(xwb, rowptr, cnt, esrc, dinv, b1, bufB, bnpart, n);
    bnred_slab_kernel<<<64, 256, 0, stream>>>(bnpart, sums, ngrp);
    bn_finalize_kernel<<<1, 128, 0, stream>>>(sums, g1, be1, bnsc, bnsc + 128, n);

    // layer 2
    gemm_kernel<128, true><<<gb, 256, 0, stream>>>(bufB, w2hi, w2lo, bnsc, bnsc + 128, dinv, xwb, n);
    agg128s_kernel<<<ngrp * 8, 256, 0, stream>>>(xwb, rowptr, cnt, esrc, dinv, b2, bufB, bnpart, n);
    bnred_slab_kernel<<<64, 256, 0, stream>>>(bnpart, sums + 256, ngrp);
    bn_finalize_kernel<<<1, 128, 0, stream>>>(sums + 256, g2, be2, bnsc + 256, bnsc + 384, n);

    // layer 3: gcn(relu(bn2(h)), W3) + b3  -> d_out  (row-major xw, agg64)
    gemm_kernel<64, false><<<gb, 256, 0, stream>>>(bufB, w3hi, w3lo, bnsc + 256, bnsc + 384, dinv, xwb, n);
    agg64_kernel<<<ab, 256, 0, stream>>>(xwb, rowptr, cnt, esrc, dinv, b3, (float*)d_out, n);
}